// Round 3
// baseline (103.935 us; speedup 1.0000x reference)
//
#include <hip/hip_runtime.h>
#include <math.h>

// MinibatchDiscrimination: B=512, IN=512, OUT=100, K=5
//   M = x @ T.view(512,500)                                  [512,500]
//   out[j,o] = sum_i exp(-sum_k |M[i,o,k]-M[j,o,k]|) - 1     [512,100]
//
// Pipeline (2 dispatches — R2 analysis: dur_us tracks dispatch count +
// 2x41us poison fills, not kernel bodies; each dispatch gap ~10us):
//  k1 gemm     : K-split x8, 64x64 tiles, 4x4 micro, b128 LDS reads
//                -> Mpart[8][512][500]                        (512 blocks)
//  k2 pairfused: per (o, 64-j chunk) block — stages its own Mpart slice,
//                sums the 8 K-split partials in registers (kills the old
//                reduce kernel + M8 round-trip), scales by log2(e), then
//                pairwise L1 + exp2 + i-reduction.  Block-id swizzle
//                clusters the 8 jc-blocks of each o on ONE XCD so the
//                shared 80KB Mpart slice stays L2-resident (per-XCD
//                footprint ~3.3MB < 4MB L2).

#define NB    512
#define NIN   512
#define NOUT  100
#define KDIM  5
#define NCOL  (NOUT*KDIM)       // 500
#define KZ    8                 // K-split factor
#define MP_ELEMS (NB*NCOL)      // 256000 per partial
#define LOG2E 1.4426950408889634f

// ---------------- Kernel 1: partial GEMM, 64x64 tile, K=64 per block
__global__ __launch_bounds__(256) void gemm_kernel(const float* __restrict__ A,
                                                   const float* __restrict__ Bm,
                                                   float* __restrict__ Mpart) {
    // stride 68 words: float4 rows stay 16B-aligned (68*4 % 16 == 0)
    __shared__ float As[64][68];
    __shared__ float Bs[64][68];

    const int tx = threadIdx.x;            // 0..15 (n)
    const int ty = threadIdx.y;            // 0..15 (m)
    const int tid = ty * 16 + tx;
    const int bn = blockIdx.x * 64;        // n-tile
    const int bm = blockIdx.y * 64;        // m-tile
    const int kz = blockIdx.z;             // 0..7
    const int kt = kz * 64;                // k-chunk

    // stage A tile: 64 rows x 64 k (1024 float4, coalesced)
    #pragma unroll
    for (int l = 0; l < 4; ++l) {
        int idx = tid + l * 256;
        int row = idx >> 4, q = idx & 15;
        float4 v = *reinterpret_cast<const float4*>(&A[(bm + row) * NIN + kt + q * 4]);
        *reinterpret_cast<float4*>(&As[row][q * 4]) = v;
    }
    // stage B tile: 64 k-rows x 64 n (guarded at col>=500)
    #pragma unroll
    for (int l = 0; l < 4; ++l) {
        int idx = tid + l * 256;
        int row = idx >> 4, q = idx & 15;
        int col = bn + q * 4;
        float4 v;
        if (col + 3 < NCOL) {
            v = *reinterpret_cast<const float4*>(&Bm[(kt + row) * NCOL + col]);
        } else {
            v.x = (col + 0 < NCOL) ? Bm[(kt + row) * NCOL + col + 0] : 0.f;
            v.y = (col + 1 < NCOL) ? Bm[(kt + row) * NCOL + col + 1] : 0.f;
            v.z = (col + 2 < NCOL) ? Bm[(kt + row) * NCOL + col + 2] : 0.f;
            v.w = (col + 3 < NCOL) ? Bm[(kt + row) * NCOL + col + 3] : 0.f;
        }
        *reinterpret_cast<float4*>(&Bs[row][q * 4]) = v;
    }
    __syncthreads();

    float acc[4][4];
    #pragma unroll
    for (int i = 0; i < 4; ++i)
        #pragma unroll
        for (int j = 0; j < 4; ++j) acc[i][j] = 0.f;

    // 4-k-unrolled inner loop: all LDS reads are ds_read_b128
    #pragma unroll 4
    for (int k = 0; k < 64; k += 4) {
        float4 a4[4], b4[4];
        #pragma unroll
        for (int i = 0; i < 4; ++i)
            a4[i] = *reinterpret_cast<const float4*>(&As[ty * 4 + i][k]);   // A[m_i][k..k+3]
        #pragma unroll
        for (int kk = 0; kk < 4; ++kk)
            b4[kk] = *reinterpret_cast<const float4*>(&Bs[k + kk][tx * 4]); // B[k+kk][n..n+3]
        #pragma unroll
        for (int kk = 0; kk < 4; ++kk) {
            const float* bp = reinterpret_cast<const float*>(&b4[kk]);
            #pragma unroll
            for (int i = 0; i < 4; ++i) {
                const float a = reinterpret_cast<const float*>(&a4[i])[kk];
                #pragma unroll
                for (int j = 0; j < 4; ++j) acc[i][j] += a * bp[j];
            }
        }
    }

    // epilogue: plain coalesced stores into this kz's partial buffer
    float* C = Mpart + kz * MP_ELEMS;
    #pragma unroll
    for (int i = 0; i < 4; ++i) {
        const int row = bm + ty * 4 + i;
        const int col0 = bn + tx * 4;
        if (col0 + 3 < NCOL) {
            float4 v = make_float4(acc[i][0], acc[i][1], acc[i][2], acc[i][3]);
            *reinterpret_cast<float4*>(&C[row * NCOL + col0]) = v;
        } else {
            #pragma unroll
            for (int j = 0; j < 4; ++j)
                if (col0 + j < NCOL) C[row * NCOL + col0 + j] = acc[i][j];
        }
    }
}

// ---------------- Kernel 2: fused reduce + pairwise L1 + exp2 + i-reduce
// Swizzled grid of 832 (32 idle): wg = (o%8) + 8*jc + 64*(o/8) so that
// wg%8 (the XCD round-robin residue) is constant for all 8 jc-blocks of
// an o — the shared Mpart slice is fetched to one XCD's L2 and reused.
// Per block: stage Ms[b][k] = log2(e) * sum_z Mpart[z][b][o*5+k], then
// 256 threads = 32 j-lanes x 2 j each x 8 i-splits (64 i each).
__global__ __launch_bounds__(256) void pairfused_kernel(const float* __restrict__ Mpart,
                                                        float* __restrict__ out) {
    __shared__ float Ms[NB * 8];      // 16 KiB (stride 8: b128-aligned rows)
    __shared__ float red[64][9];      // +1 pad: conflict-free column writes

    const int wg = blockIdx.x;        // 0..831 swizzled
    const int o  = (wg & 7) + 8 * (wg >> 6);
    const int jc = (wg >> 3) & 7;
    if (o >= NOUT) return;            // block-uniform exit (q=12, r>=4 holes)

    const int tid = threadIdx.x;      // 0..255

    // ---- stage + z-reduce: thread owns rows b0, b0+1 (256 thr x 2 = 512)
    {
        const int b0 = tid * 2;
        float s0[5] = {0.f, 0.f, 0.f, 0.f, 0.f};
        float s1[5] = {0.f, 0.f, 0.f, 0.f, 0.f};
        const float* base = Mpart + (size_t)o * KDIM + (size_t)b0 * NCOL;
        #pragma unroll
        for (int z = 0; z < KZ; ++z) {
            const float* p0 = base + (size_t)z * MP_ELEMS;
            const float* p1 = p0 + NCOL;
            #pragma unroll
            for (int k = 0; k < 5; ++k) s0[k] += p0[k];
            #pragma unroll
            for (int k = 0; k < 5; ++k) s1[k] += p1[k];
        }
        #pragma unroll
        for (int k = 0; k < 5; ++k) Ms[b0 * 8 + k]       = s0[k] * LOG2E;
        #pragma unroll
        for (int k = 0; k < 5; ++k) Ms[(b0 + 1) * 8 + k] = s1[k] * LOG2E;
    }
    __syncthreads();

    const int jl = tid & 31;          // local j lane
    const int ig = tid >> 5;          // i-split group 0..7
    const int jA = jc * 64 + jl;
    const int jB = jA + 32;
    const int i0 = ig * 64;

    const float4 av = *reinterpret_cast<const float4*>(&Ms[jA * 8]);
    const float  a4 = Ms[jA * 8 + 4];
    const float4 bv = *reinterpret_cast<const float4*>(&Ms[jB * 8]);
    const float  b4 = Ms[jB * 8 + 4];

    float accA = 0.0f, accB = 0.0f;
    #pragma unroll 8
    for (int i = i0; i < i0 + 64; ++i) {
        float4 v = *reinterpret_cast<const float4*>(&Ms[i * 8]);
        float v4 = Ms[i * 8 + 4];
        float nA = fabsf(v.x - av.x) + fabsf(v.y - av.y) + fabsf(v.z - av.z)
                 + fabsf(v.w - av.w) + fabsf(v4 - a4);
        float nB = fabsf(v.x - bv.x) + fabsf(v.y - bv.y) + fabsf(v.z - bv.z)
                 + fabsf(v.w - bv.w) + fabsf(v4 - b4);
        accA += exp2f(-nA);            // Ms pre-scaled by log2(e): == exp(-norm)
        accB += exp2f(-nB);            // lowers to bare v_exp_f32
    }

    red[jl][ig]      = accA;
    red[jl + 32][ig] = accB;
    __syncthreads();

    if (tid < 64) {
        float tot = -1.0f;            // remove exp(0) self-term
        #pragma unroll
        for (int g = 0; g < 8; ++g) tot += red[tid][g];
        out[(jc * 64 + tid) * NOUT + o] = tot;
    }
}

extern "C" void kernel_launch(void* const* d_in, const int* in_sizes, int n_in,
                              void* d_out, int out_size, void* d_ws, size_t ws_size,
                              hipStream_t stream) {
    const float* x = (const float*)d_in[0];   // [512,512]
    const float* T = (const float*)d_in[1];   // [512,500]
    float* Mpart = (float*)d_ws;              // 8 * 1.024 MB
    float* out   = (float*)d_out;             // [512,100]

    gemm_kernel<<<dim3(8, 8, KZ), dim3(16, 16), 0, stream>>>(x, T, Mpart);
    pairfused_kernel<<<832, 256, 0, stream>>>(Mpart, out);
}

// Round 4
// 86.627 us; speedup vs baseline: 1.1998x; 1.1998x over previous
//
#include <hip/hip_runtime.h>
#include <math.h>

// MinibatchDiscrimination: B=512, IN=512, OUT=100, K=5
//   M = x @ T.view(512,500)                                  [512,500]
//   out[j,o] = sum_i exp(-sum_k |M[i,o,k]-M[j,o,k]|) - 1     [512,100]
//
// Pipeline (3 dispatches). R3 post-mortem: fusing reduce into pairwise
// regressed +18us (uncoalesced 20B strided staging, ~6.8M VMEM instrs);
// dispatch gaps measured small (~2us). Reverted. dur_us model:
//   dur ~= poison fills (82-87us, untouchable) + kernel bodies - ~12us.
//  k1 gemm   : K-split x8, 64x64 tiles, 4x4 micro, b128 LDS reads
//              -> Mpart[8][512][500]                          (512 blocks)
//  k2 reduce : float4-vectorized sum of 8 partials -> M8[512][800]
//              (padded layout M8[b][o*8+k]), pre-scaled by log2(e) so
//              pairwise uses bare v_exp_f32 (exp2), no per-pair mul
//  k3 pair   : per (o, 128-j chunk) block, 4 j's PER THREAD — the same
//              broadcast b128+b32 read of row i feeds FOUR pairs; DS
//              drops to ~1/4 of the 1-j version and the kernel becomes
//              VALU-bound at its ~4us floor (L1+exp math irreducible).

#define NB    512
#define NIN   512
#define NOUT  100
#define KDIM  5
#define NCOL  (NOUT*KDIM)       // 500
#define KZ    8                 // K-split factor
#define MP_ELEMS (NB*NCOL)      // 256000 per partial
#define M8_LD 800               // padded row stride of M8 (8 floats per o)
#define LOG2E 1.4426950408889634f

// ---------------- Kernel 1: partial GEMM, 64x64 tile, K=64 per block
__global__ __launch_bounds__(256) void gemm_kernel(const float* __restrict__ A,
                                                   const float* __restrict__ Bm,
                                                   float* __restrict__ Mpart) {
    // stride 68 words: float4 rows stay 16B-aligned (68*4 % 16 == 0)
    __shared__ float As[64][68];
    __shared__ float Bs[64][68];

    const int tx = threadIdx.x;            // 0..15 (n)
    const int ty = threadIdx.y;            // 0..15 (m)
    const int tid = ty * 16 + tx;
    const int bn = blockIdx.x * 64;        // n-tile
    const int bm = blockIdx.y * 64;        // m-tile
    const int kz = blockIdx.z;             // 0..7
    const int kt = kz * 64;                // k-chunk

    // stage A tile: 64 rows x 64 k (1024 float4, coalesced)
    #pragma unroll
    for (int l = 0; l < 4; ++l) {
        int idx = tid + l * 256;
        int row = idx >> 4, q = idx & 15;
        float4 v = *reinterpret_cast<const float4*>(&A[(bm + row) * NIN + kt + q * 4]);
        *reinterpret_cast<float4*>(&As[row][q * 4]) = v;
    }
    // stage B tile: 64 k-rows x 64 n (guarded at col>=500)
    #pragma unroll
    for (int l = 0; l < 4; ++l) {
        int idx = tid + l * 256;
        int row = idx >> 4, q = idx & 15;
        int col = bn + q * 4;
        float4 v;
        if (col + 3 < NCOL) {
            v = *reinterpret_cast<const float4*>(&Bm[(kt + row) * NCOL + col]);
        } else {
            v.x = (col + 0 < NCOL) ? Bm[(kt + row) * NCOL + col + 0] : 0.f;
            v.y = (col + 1 < NCOL) ? Bm[(kt + row) * NCOL + col + 1] : 0.f;
            v.z = (col + 2 < NCOL) ? Bm[(kt + row) * NCOL + col + 2] : 0.f;
            v.w = (col + 3 < NCOL) ? Bm[(kt + row) * NCOL + col + 3] : 0.f;
        }
        *reinterpret_cast<float4*>(&Bs[row][q * 4]) = v;
    }
    __syncthreads();

    float acc[4][4];
    #pragma unroll
    for (int i = 0; i < 4; ++i)
        #pragma unroll
        for (int j = 0; j < 4; ++j) acc[i][j] = 0.f;

    // 4-k-unrolled inner loop: all LDS reads are ds_read_b128
    #pragma unroll 4
    for (int k = 0; k < 64; k += 4) {
        float4 a4[4], b4[4];
        #pragma unroll
        for (int i = 0; i < 4; ++i)
            a4[i] = *reinterpret_cast<const float4*>(&As[ty * 4 + i][k]);   // A[m_i][k..k+3]
        #pragma unroll
        for (int kk = 0; kk < 4; ++kk)
            b4[kk] = *reinterpret_cast<const float4*>(&Bs[k + kk][tx * 4]); // B[k+kk][n..n+3]
        #pragma unroll
        for (int kk = 0; kk < 4; ++kk) {
            const float* bp = reinterpret_cast<const float*>(&b4[kk]);
            #pragma unroll
            for (int i = 0; i < 4; ++i) {
                const float a = reinterpret_cast<const float*>(&a4[i])[kk];
                #pragma unroll
                for (int j = 0; j < 4; ++j) acc[i][j] += a * bp[j];
            }
        }
    }

    // epilogue: plain coalesced stores into this kz's partial buffer
    float* C = Mpart + kz * MP_ELEMS;
    #pragma unroll
    for (int i = 0; i < 4; ++i) {
        const int row = bm + ty * 4 + i;
        const int col0 = bn + tx * 4;
        if (col0 + 3 < NCOL) {
            float4 v = make_float4(acc[i][0], acc[i][1], acc[i][2], acc[i][3]);
            *reinterpret_cast<float4*>(&C[row * NCOL + col0]) = v;
        } else {
            #pragma unroll
            for (int j = 0; j < 4; ++j)
                if (col0 + j < NCOL) C[row * NCOL + col0 + j] = acc[i][j];
        }
    }
}

// ---------------- Kernel 2: sum KZ partials -> M8[512][800] (M8[b][o*8+k])
// One float4 per thread: 500 = 4*125, so a float4 never straddles a row.
// Pre-scales by log2(e): pairwise then computes exp2(-norm2) == exp(-norm)
// with a bare v_exp_f32 (no per-pair base-conversion mul).
__global__ __launch_bounds__(256) void reduce_kernel(const float* __restrict__ Mpart,
                                                     float* __restrict__ M8) {
    const unsigned n = blockIdx.x * 256 + threadIdx.x;    // 0..63999 float4 idx
    const float4* P = reinterpret_cast<const float4*>(Mpart);
    float4 s = P[n];
    #pragma unroll
    for (int z = 1; z < KZ; ++z) {
        float4 v = P[z * (MP_ELEMS / 4) + n];
        s.x += v.x; s.y += v.y; s.z += v.z; s.w += v.w;
    }
    const unsigned b  = n / 125;           // row
    const unsigned c  = (n - b * 125) * 4; // col of element 0
    const float sv[4] = {s.x * LOG2E, s.y * LOG2E, s.z * LOG2E, s.w * LOG2E};
    #pragma unroll
    for (int e = 0; e < 4; ++e) {
        const unsigned col = c + e;
        const unsigned o   = col / KDIM;
        const unsigned kk  = col - o * KDIM;
        M8[b * M8_LD + o * 8 + kk] = sv[e];
    }
}

// ---------------- Kernel 3: pairwise L1 + exp2 + reduce over i
// grid (100, 4): block = (o, 128 j's). 256 threads = 32 j-lanes x 4 j each,
// 8 i-splits (64 i each). One broadcast b128+b32 pair per i feeds FOUR
// (i,j) pairs; per-iter loop/address overhead amortizes 4x. VALU-bound.
__global__ __launch_bounds__(256) void pairwise_kernel(const float* __restrict__ M8,
                                                       float* __restrict__ out) {
    __shared__ float Ms[NB * 8];      // 16 KiB
    __shared__ float red[128][9];     // +1 pad: conflict-free column writes

    const int o   = blockIdx.x;       // 0..99
    const int jc  = blockIdx.y;       // 0..3
    const int tid = threadIdx.x;      // 0..255

    // stage M8[:, o*8 .. o*8+7] -> Ms; lane pairs read the two float4s of a row
    {
        const int half = tid & 1;
        for (int b = tid >> 1; b < NB; b += 128) {
            const float* src = M8 + b * M8_LD + o * 8 + half * 4;
            *reinterpret_cast<float4*>(&Ms[b * 8 + half * 4]) =
                *reinterpret_cast<const float4*>(src);
        }
    }
    __syncthreads();

    const int jl = tid & 31;          // local j lane
    const int ig = tid >> 5;          // i-split group 0..7
    const int j0 = jc * 128 + jl;     // j0, j0+32, j0+64, j0+96
    const int i0 = ig * 64;

    float4 jv[4]; float j4[4];
    #pragma unroll
    for (int q = 0; q < 4; ++q) {
        jv[q] = *reinterpret_cast<const float4*>(&Ms[(j0 + q * 32) * 8]);
        j4[q] = Ms[(j0 + q * 32) * 8 + 4];
    }

    float acc[4] = {0.f, 0.f, 0.f, 0.f};
    #pragma unroll 4
    for (int i = i0; i < i0 + 64; ++i) {
        float4 v = *reinterpret_cast<const float4*>(&Ms[i * 8]);
        float v4 = Ms[i * 8 + 4];
        #pragma unroll
        for (int q = 0; q < 4; ++q) {
            float n = fabsf(v.x - jv[q].x) + fabsf(v.y - jv[q].y)
                    + fabsf(v.z - jv[q].z) + fabsf(v.w - jv[q].w)
                    + fabsf(v4 - j4[q]);
            acc[q] += exp2f(-n);       // Ms pre-scaled by log2(e): == exp(-norm)
        }
    }

    #pragma unroll
    for (int q = 0; q < 4; ++q) red[jl + q * 32][ig] = acc[q];
    __syncthreads();

    if (tid < 128) {
        float tot = -1.0f;            // remove exp(0) self-term
        #pragma unroll
        for (int g = 0; g < 8; ++g) tot += red[tid][g];
        out[(jc * 128 + tid) * NOUT + o] = tot;
    }
}

extern "C" void kernel_launch(void* const* d_in, const int* in_sizes, int n_in,
                              void* d_out, int out_size, void* d_ws, size_t ws_size,
                              hipStream_t stream) {
    const float* x = (const float*)d_in[0];   // [512,512]
    const float* T = (const float*)d_in[1];   // [512,500]
    float* Mpart = (float*)d_ws;                          // 8 * 1.024 MB
    float* M8    = (float*)d_ws + KZ * MP_ELEMS;          // 512*800*4 = 1.6 MB
    float* out   = (float*)d_out;                         // [512,100]

    gemm_kernel<<<dim3(8, 8, KZ), dim3(16, 16), 0, stream>>>(x, T, Mpart);
    reduce_kernel<<<250, 256, 0, stream>>>(Mpart, M8);
    pairwise_kernel<<<dim3(NOUT, 4), 256, 0, stream>>>(M8, out);
}

// Round 5
// 84.449 us; speedup vs baseline: 1.2307x; 1.0258x over previous
//
#include <hip/hip_runtime.h>
#include <math.h>

// MinibatchDiscrimination: B=512, IN=512, OUT=100, K=5
//   M = x @ T.view(512,500)                                  [512,500]
//   out[j,o] = sum_i exp(-sum_k |M[i,o,k]-M[j,o,k]|) - 1     [512,100]
//
// Pipeline (3 dispatches).
// R3 post-mortem: fusing reduce into pairwise regressed +18us
//   (uncoalesced 20B strided staging); dispatch gaps measured ~2us.
// R4 post-mortem: 2j and 4j pairwise identical (86.2/86.6) but both
//   +4us vs the 82.5 baseline whose only systematic difference was
//   __expf vs exp2f+LOG2E-prescale -> exp2f (no fast-math) does NOT
//   lower to bare v_exp_f32; it carries fixup guards x26.2M calls.
// R5: keep 4j/thread structure, revert math to __expf (v_mul+v_exp_f32,
//   proven at 82.5); reduce kernel back to plain sums (no prescale).
//  k1 gemm   : K-split x8, 64x64 tiles, 4x4 micro, b128 LDS reads
//              -> Mpart[8][512][500]                          (512 blocks)
//  k2 reduce : float4-vectorized sum of 8 partials -> M8[512][800]
//              (padded layout M8[b][o*8+k])                   (250 blocks)
//  k3 pair   : per (o, 128-j chunk) block, 4 j's PER THREAD — one
//              broadcast b128+b32 read of row i feeds FOUR pairs.

#define NB    512
#define NIN   512
#define NOUT  100
#define KDIM  5
#define NCOL  (NOUT*KDIM)       // 500
#define KZ    8                 // K-split factor
#define MP_ELEMS (NB*NCOL)      // 256000 per partial
#define M8_LD 800               // padded row stride of M8 (8 floats per o)

// ---------------- Kernel 1: partial GEMM, 64x64 tile, K=64 per block
__global__ __launch_bounds__(256) void gemm_kernel(const float* __restrict__ A,
                                                   const float* __restrict__ Bm,
                                                   float* __restrict__ Mpart) {
    // stride 68 words: float4 rows stay 16B-aligned (68*4 % 16 == 0)
    __shared__ float As[64][68];
    __shared__ float Bs[64][68];

    const int tx = threadIdx.x;            // 0..15 (n)
    const int ty = threadIdx.y;            // 0..15 (m)
    const int tid = ty * 16 + tx;
    const int bn = blockIdx.x * 64;        // n-tile
    const int bm = blockIdx.y * 64;        // m-tile
    const int kz = blockIdx.z;             // 0..7
    const int kt = kz * 64;                // k-chunk

    // stage A tile: 64 rows x 64 k (1024 float4, coalesced)
    #pragma unroll
    for (int l = 0; l < 4; ++l) {
        int idx = tid + l * 256;
        int row = idx >> 4, q = idx & 15;
        float4 v = *reinterpret_cast<const float4*>(&A[(bm + row) * NIN + kt + q * 4]);
        *reinterpret_cast<float4*>(&As[row][q * 4]) = v;
    }
    // stage B tile: 64 k-rows x 64 n (guarded at col>=500)
    #pragma unroll
    for (int l = 0; l < 4; ++l) {
        int idx = tid + l * 256;
        int row = idx >> 4, q = idx & 15;
        int col = bn + q * 4;
        float4 v;
        if (col + 3 < NCOL) {
            v = *reinterpret_cast<const float4*>(&Bm[(kt + row) * NCOL + col]);
        } else {
            v.x = (col + 0 < NCOL) ? Bm[(kt + row) * NCOL + col + 0] : 0.f;
            v.y = (col + 1 < NCOL) ? Bm[(kt + row) * NCOL + col + 1] : 0.f;
            v.z = (col + 2 < NCOL) ? Bm[(kt + row) * NCOL + col + 2] : 0.f;
            v.w = (col + 3 < NCOL) ? Bm[(kt + row) * NCOL + col + 3] : 0.f;
        }
        *reinterpret_cast<float4*>(&Bs[row][q * 4]) = v;
    }
    __syncthreads();

    float acc[4][4];
    #pragma unroll
    for (int i = 0; i < 4; ++i)
        #pragma unroll
        for (int j = 0; j < 4; ++j) acc[i][j] = 0.f;

    // 4-k-unrolled inner loop: all LDS reads are ds_read_b128
    #pragma unroll 4
    for (int k = 0; k < 64; k += 4) {
        float4 a4[4], b4[4];
        #pragma unroll
        for (int i = 0; i < 4; ++i)
            a4[i] = *reinterpret_cast<const float4*>(&As[ty * 4 + i][k]);   // A[m_i][k..k+3]
        #pragma unroll
        for (int kk = 0; kk < 4; ++kk)
            b4[kk] = *reinterpret_cast<const float4*>(&Bs[k + kk][tx * 4]); // B[k+kk][n..n+3]
        #pragma unroll
        for (int kk = 0; kk < 4; ++kk) {
            const float* bp = reinterpret_cast<const float*>(&b4[kk]);
            #pragma unroll
            for (int i = 0; i < 4; ++i) {
                const float a = reinterpret_cast<const float*>(&a4[i])[kk];
                #pragma unroll
                for (int j = 0; j < 4; ++j) acc[i][j] += a * bp[j];
            }
        }
    }

    // epilogue: plain coalesced stores into this kz's partial buffer
    float* C = Mpart + kz * MP_ELEMS;
    #pragma unroll
    for (int i = 0; i < 4; ++i) {
        const int row = bm + ty * 4 + i;
        const int col0 = bn + tx * 4;
        if (col0 + 3 < NCOL) {
            float4 v = make_float4(acc[i][0], acc[i][1], acc[i][2], acc[i][3]);
            *reinterpret_cast<float4*>(&C[row * NCOL + col0]) = v;
        } else {
            #pragma unroll
            for (int j = 0; j < 4; ++j)
                if (col0 + j < NCOL) C[row * NCOL + col0 + j] = acc[i][j];
        }
    }
}

// ---------------- Kernel 2: sum KZ partials -> M8[512][800] (M8[b][o*8+k])
// One float4 per thread: 500 = 4*125, so a float4 never straddles a row.
__global__ __launch_bounds__(256) void reduce_kernel(const float* __restrict__ Mpart,
                                                     float* __restrict__ M8) {
    const unsigned n = blockIdx.x * 256 + threadIdx.x;    // 0..63999 float4 idx
    const float4* P = reinterpret_cast<const float4*>(Mpart);
    float4 s = P[n];
    #pragma unroll
    for (int z = 1; z < KZ; ++z) {
        float4 v = P[z * (MP_ELEMS / 4) + n];
        s.x += v.x; s.y += v.y; s.z += v.z; s.w += v.w;
    }
    const unsigned b  = n / 125;           // row
    const unsigned c  = (n - b * 125) * 4; // col of element 0
    const float sv[4] = {s.x, s.y, s.z, s.w};
    #pragma unroll
    for (int e = 0; e < 4; ++e) {
        const unsigned col = c + e;
        const unsigned o   = col / KDIM;
        const unsigned kk  = col - o * KDIM;
        M8[b * M8_LD + o * 8 + kk] = sv[e];
    }
}

// ---------------- Kernel 3: pairwise L1 + exp + reduce over i
// grid (100, 4): block = (o, 128 j's). 256 threads = 32 j-lanes x 4 j each,
// 8 i-splits (64 i each). One broadcast b128+b32 pair per i feeds FOUR
// (i,j) pairs. __expf = v_mul(log2e) + bare v_exp_f32 (proven at 82.5us;
// exp2f carries non-fast-math fixup guards — R4 post-mortem).
__global__ __launch_bounds__(256) void pairwise_kernel(const float* __restrict__ M8,
                                                       float* __restrict__ out) {
    __shared__ float Ms[NB * 8];      // 16 KiB
    __shared__ float red[128][9];     // +1 pad: conflict-free column writes

    const int o   = blockIdx.x;       // 0..99
    const int jc  = blockIdx.y;       // 0..3
    const int tid = threadIdx.x;      // 0..255

    // stage M8[:, o*8 .. o*8+7] -> Ms; lane pairs read the two float4s of a row
    {
        const int half = tid & 1;
        for (int b = tid >> 1; b < NB; b += 128) {
            const float* src = M8 + b * M8_LD + o * 8 + half * 4;
            *reinterpret_cast<float4*>(&Ms[b * 8 + half * 4]) =
                *reinterpret_cast<const float4*>(src);
        }
    }
    __syncthreads();

    const int jl = tid & 31;          // local j lane
    const int ig = tid >> 5;          // i-split group 0..7
    const int j0 = jc * 128 + jl;     // j0, j0+32, j0+64, j0+96
    const int i0 = ig * 64;

    float4 jv[4]; float j4[4];
    #pragma unroll
    for (int q = 0; q < 4; ++q) {
        jv[q] = *reinterpret_cast<const float4*>(&Ms[(j0 + q * 32) * 8]);
        j4[q] = Ms[(j0 + q * 32) * 8 + 4];
    }

    float acc[4] = {0.f, 0.f, 0.f, 0.f};
    #pragma unroll 4
    for (int i = i0; i < i0 + 64; ++i) {
        float4 v = *reinterpret_cast<const float4*>(&Ms[i * 8]);
        float v4 = Ms[i * 8 + 4];
        #pragma unroll
        for (int q = 0; q < 4; ++q) {
            float n = fabsf(v.x - jv[q].x) + fabsf(v.y - jv[q].y)
                    + fabsf(v.z - jv[q].z) + fabsf(v.w - jv[q].w)
                    + fabsf(v4 - j4[q]);
            acc[q] += __expf(-n);
        }
    }

    #pragma unroll
    for (int q = 0; q < 4; ++q) red[jl + q * 32][ig] = acc[q];
    __syncthreads();

    if (tid < 128) {
        float tot = -1.0f;            // remove exp(0) self-term
        #pragma unroll
        for (int g = 0; g < 8; ++g) tot += red[tid][g];
        out[(jc * 128 + tid) * NOUT + o] = tot;
    }
}

extern "C" void kernel_launch(void* const* d_in, const int* in_sizes, int n_in,
                              void* d_out, int out_size, void* d_ws, size_t ws_size,
                              hipStream_t stream) {
    const float* x = (const float*)d_in[0];   // [512,512]
    const float* T = (const float*)d_in[1];   // [512,500]
    float* Mpart = (float*)d_ws;                          // 8 * 1.024 MB
    float* M8    = (float*)d_ws + KZ * MP_ELEMS;          // 512*800*4 = 1.6 MB
    float* out   = (float*)d_out;                         // [512,100]

    gemm_kernel<<<dim3(8, 8, KZ), dim3(16, 16), 0, stream>>>(x, T, Mpart);
    reduce_kernel<<<250, 256, 0, stream>>>(Mpart, M8);
    pairwise_kernel<<<dim3(NOUT, 4), 256, 0, stream>>>(M8, out);
}

// Round 6
// 82.649 us; speedup vs baseline: 1.2576x; 1.0218x over previous
//
#include <hip/hip_runtime.h>
#include <math.h>

// MinibatchDiscrimination: B=512, IN=512, OUT=100, K=5
//   M = x @ T.view(512,500)                                  [512,500]
//   out[j,o] = sum_i exp(-sum_k |M[i,o,k]-M[j,o,k]|) - 1     [512,100]
//
// FINAL: byte-identical revert to the best harness-verified config
// (82.5us). Session findings (R0-R5):
//  - dur_us is floored by 2x256MiB harness poison fills (41us each at
//    ~6.5TB/s); kernel bodies (~12-14us) are almost fully hidden
//    (residual over fills: +0.4us here, +17us when bodies grew to 32us).
//  - exp2f without fast-math carries fixup guards (+2.2us over __expf
//    at 26.2M calls); __expf = v_mul(log2e)+bare v_exp_f32 is optimal.
//  - j-blocking pairwise (2j/4j per thread) cuts DS traffic but shrinks
//    the grid (400-800 blocks, <=3.1/CU) — load-balance loss >= DS gain.
//    1600 blocks @ 6.25/CU wins.
//  - Fusing reduce into pairwise (20B strided staging) regressed +18us.
//
//  k1 gemm   : K-split x8, 64x64 tiles, 4x4 micro, b128 LDS reads
//              -> Mpart[8][512][500]                          (512 blocks)
//  k2 reduce : float4-vectorized sum of 8 partials -> M8[512][800]
//              (padded layout M8[b][o*8+k])                   (250 blocks)
//  k3 pair   : per (o, 32-j chunk) block, LDS-staged i-loop   (1600 blocks)

#define NB    512
#define NIN   512
#define NOUT  100
#define KDIM  5
#define NCOL  (NOUT*KDIM)       // 500
#define KZ    8                 // K-split factor
#define MP_ELEMS (NB*NCOL)      // 256000 per partial
#define M8_LD 800               // padded row stride of M8 (8 floats per o)

// ---------------- Kernel 1: partial GEMM, 64x64 tile, K=64 per block
__global__ __launch_bounds__(256) void gemm_kernel(const float* __restrict__ A,
                                                   const float* __restrict__ Bm,
                                                   float* __restrict__ Mpart) {
    // stride 68 words: float4 rows stay 16B-aligned (68*4 % 16 == 0)
    __shared__ float As[64][68];
    __shared__ float Bs[64][68];

    const int tx = threadIdx.x;            // 0..15 (n)
    const int ty = threadIdx.y;            // 0..15 (m)
    const int tid = ty * 16 + tx;
    const int bn = blockIdx.x * 64;        // n-tile
    const int bm = blockIdx.y * 64;        // m-tile
    const int kz = blockIdx.z;             // 0..7
    const int kt = kz * 64;                // k-chunk

    // stage A tile: 64 rows x 64 k (1024 float4, coalesced)
    #pragma unroll
    for (int l = 0; l < 4; ++l) {
        int idx = tid + l * 256;
        int row = idx >> 4, q = idx & 15;
        float4 v = *reinterpret_cast<const float4*>(&A[(bm + row) * NIN + kt + q * 4]);
        *reinterpret_cast<float4*>(&As[row][q * 4]) = v;
    }
    // stage B tile: 64 k-rows x 64 n (guarded at col>=500)
    #pragma unroll
    for (int l = 0; l < 4; ++l) {
        int idx = tid + l * 256;
        int row = idx >> 4, q = idx & 15;
        int col = bn + q * 4;
        float4 v;
        if (col + 3 < NCOL) {
            v = *reinterpret_cast<const float4*>(&Bm[(kt + row) * NCOL + col]);
        } else {
            v.x = (col + 0 < NCOL) ? Bm[(kt + row) * NCOL + col + 0] : 0.f;
            v.y = (col + 1 < NCOL) ? Bm[(kt + row) * NCOL + col + 1] : 0.f;
            v.z = (col + 2 < NCOL) ? Bm[(kt + row) * NCOL + col + 2] : 0.f;
            v.w = (col + 3 < NCOL) ? Bm[(kt + row) * NCOL + col + 3] : 0.f;
        }
        *reinterpret_cast<float4*>(&Bs[row][q * 4]) = v;
    }
    __syncthreads();

    float acc[4][4];
    #pragma unroll
    for (int i = 0; i < 4; ++i)
        #pragma unroll
        for (int j = 0; j < 4; ++j) acc[i][j] = 0.f;

    // 4-k-unrolled inner loop: all LDS reads are ds_read_b128
    #pragma unroll 4
    for (int k = 0; k < 64; k += 4) {
        float4 a4[4], b4[4];
        #pragma unroll
        for (int i = 0; i < 4; ++i)
            a4[i] = *reinterpret_cast<const float4*>(&As[ty * 4 + i][k]);   // A[m_i][k..k+3]
        #pragma unroll
        for (int kk = 0; kk < 4; ++kk)
            b4[kk] = *reinterpret_cast<const float4*>(&Bs[k + kk][tx * 4]); // B[k+kk][n..n+3]
        #pragma unroll
        for (int kk = 0; kk < 4; ++kk) {
            const float* bp = reinterpret_cast<const float*>(&b4[kk]);
            #pragma unroll
            for (int i = 0; i < 4; ++i) {
                const float a = reinterpret_cast<const float*>(&a4[i])[kk];
                #pragma unroll
                for (int j = 0; j < 4; ++j) acc[i][j] += a * bp[j];
            }
        }
    }

    // epilogue: plain coalesced stores into this kz's partial buffer
    float* C = Mpart + kz * MP_ELEMS;
    #pragma unroll
    for (int i = 0; i < 4; ++i) {
        const int row = bm + ty * 4 + i;
        const int col0 = bn + tx * 4;
        if (col0 + 3 < NCOL) {
            float4 v = make_float4(acc[i][0], acc[i][1], acc[i][2], acc[i][3]);
            *reinterpret_cast<float4*>(&C[row * NCOL + col0]) = v;
        } else {
            #pragma unroll
            for (int j = 0; j < 4; ++j)
                if (col0 + j < NCOL) C[row * NCOL + col0 + j] = acc[i][j];
        }
    }
}

// ---------------- Kernel 2: sum KZ partials -> M8[512][800] (M8[b][o*8+k])
// One float4 per thread: 500 = 4*125, so a float4 never straddles a row.
__global__ __launch_bounds__(256) void reduce_kernel(const float* __restrict__ Mpart,
                                                     float* __restrict__ M8) {
    const unsigned n = blockIdx.x * 256 + threadIdx.x;    // 0..63999 float4 idx
    const float4* P = reinterpret_cast<const float4*>(Mpart);
    float4 s = P[n];
    #pragma unroll
    for (int z = 1; z < KZ; ++z) {
        float4 v = P[z * (MP_ELEMS / 4) + n];
        s.x += v.x; s.y += v.y; s.z += v.z; s.w += v.w;
    }
    const unsigned b  = n / 125;           // row
    const unsigned c  = (n - b * 125) * 4; // col of element 0
    const float sv[4] = {s.x, s.y, s.z, s.w};
    #pragma unroll
    for (int e = 0; e < 4; ++e) {
        const unsigned col = c + e;
        const unsigned o   = col / KDIM;
        const unsigned kk  = col - o * KDIM;
        M8[b * M8_LD + o * 8 + kk] = sv[e];
    }
}

// ---------------- Kernel 3: pairwise L1 + exp + reduce over i
// grid (100, 16): block = (o, 32 j's). 256 threads = 32 j x 8 i-splits
// (64 i each). 1600 blocks = 6.25/CU — load balance beats DS savings of
// j-blocked variants (R5 post-mortem).
__global__ __launch_bounds__(256) void pairwise_kernel(const float* __restrict__ M8,
                                                       float* __restrict__ out) {
    __shared__ float Ms[NB * 8];      // 16 KiB
    __shared__ float partial[256];

    const int o   = blockIdx.x;       // 0..99
    const int jc  = blockIdx.y;       // 0..15
    const int tid = threadIdx.x;      // 0..255

    // stage M8[:, o*8 .. o*8+7] -> Ms; lane pairs read the two float4s of a row
    {
        const int half = tid & 1;
        for (int b = tid >> 1; b < NB; b += 128) {
            const float* src = M8 + b * M8_LD + o * 8 + half * 4;
            *reinterpret_cast<float4*>(&Ms[b * 8 + half * 4]) =
                *reinterpret_cast<const float4*>(src);
        }
    }
    __syncthreads();

    const int j  = jc * 32 + (tid & 31);
    const int i0 = (tid >> 5) * 64;

    const float4 jv = *reinterpret_cast<const float4*>(&Ms[j * 8]);
    const float  j4 = Ms[j * 8 + 4];

    float acc = 0.0f;
    #pragma unroll 8
    for (int i = i0; i < i0 + 64; ++i) {
        float4 v = *reinterpret_cast<const float4*>(&Ms[i * 8]);
        float v4 = Ms[i * 8 + 4];
        float norm = fabsf(v.x - jv.x) + fabsf(v.y - jv.y) + fabsf(v.z - jv.z)
                   + fabsf(v.w - jv.w) + fabsf(v4 - j4);
        acc += __expf(-norm);
    }

    partial[tid] = acc;
    __syncthreads();

    if (tid < 32) {
        float tot = -1.0f;            // remove exp(0) self-term
        #pragma unroll
        for (int s = 0; s < 8; ++s) tot += partial[tid + s * 32];
        out[(jc * 32 + tid) * NOUT + o] = tot;
    }
}

extern "C" void kernel_launch(void* const* d_in, const int* in_sizes, int n_in,
                              void* d_out, int out_size, void* d_ws, size_t ws_size,
                              hipStream_t stream) {
    const float* x = (const float*)d_in[0];   // [512,512]
    const float* T = (const float*)d_in[1];   // [512,500]
    float* Mpart = (float*)d_ws;                          // 8 * 1.024 MB
    float* M8    = (float*)d_ws + KZ * MP_ELEMS;          // 512*800*4 = 1.6 MB
    float* out   = (float*)d_out;                         // [512,100]

    gemm_kernel<<<dim3(8, 8, KZ), dim3(16, 16), 0, stream>>>(x, T, Mpart);
    reduce_kernel<<<250, 256, 0, stream>>>(Mpart, M8);
    pairwise_kernel<<<dim3(NOUT, 16), 256, 0, stream>>>(M8, out);
}